// Round 13
// baseline (1008.431 us; speedup 1.0000x reference)
//
#include <hip/hip_runtime.h>
#include <hip/hip_bf16.h>
#include <math.h>

#define BBATCH 4
#define NHEAD  8
#define TSEQ   2048
#define NDIM   256
#define DDIM   512

typedef float f32x4 __attribute__((ext_vector_type(4)));
typedef short bf16x8 __attribute__((ext_vector_type(8)));

typedef __attribute__((address_space(3))) unsigned int lds_uint;
typedef __attribute__((address_space(1))) unsigned int g_uint;

__device__ __forceinline__ unsigned short f2bf(float f) {
  __hip_bfloat16 h = __float2bfloat16(f);
  return *reinterpret_cast<unsigned short*>(&h);
}
__device__ __forceinline__ float bf2f(unsigned short u) {
  __hip_bfloat16 h;
  *reinterpret_cast<unsigned short*>(&h) = u;
  return __bfloat162float(h);
}
__device__ __forceinline__ f32x4 mfma16(bf16x8 a, bf16x8 b, f32x4 c) {
  return __builtin_amdgcn_mfma_f32_16x16x32_bf16(a, b, c, 0, 0, 0);
}

// Kr swizzle (two-level, spreads both row-low and row-mid bits)
#define KSW(t) (((((t) & 7) ^ (((t) >> 3) & 3))) << 4)

// ---------------- Kernel 1: RoPE(Q) -> QR bf16 --------------------------
__global__ __launch_bounds__(256) void rope_kernel(const float* __restrict__ Q,
                                                   unsigned short* __restrict__ QR) {
  long idx = (long)blockIdx.x * 256 + threadIdx.x;
  int pair = (int)(idx & 127);
  long row = idx >> 7;
  int t = (int)(row & (TSEQ - 1));
  float2 q = reinterpret_cast<const float2*>(Q)[idx];
  float freq = exp2f(-(float)pair * 0.125f) * 0.15915494309189535f;
  float phase = (float)t * freq;
  float ph = (phase - floorf(phase)) * 6.283185307179586f;
  float s, c;
  sincosf(ph, &s, &c);
  float o0 = q.x * c - q.y * s;
  float o1 = q.y * c + q.x * s;
  unsigned int pk = (unsigned int)f2bf(o0) | ((unsigned int)f2bf(o1) << 16);
  reinterpret_cast<unsigned int*>(QR)[idx] = pk;
}

// ---------------- Kernel 2: transpose + cast f32[R][C] -> bf16[C][R] ----
__global__ __launch_bounds__(256) void transpose_cast_kernel(
    const float* __restrict__ in, unsigned short* __restrict__ out, int R, int C) {
  __shared__ float tile[64][65];
  long mat = blockIdx.z;
  const float* src = in + mat * (long)R * C;
  unsigned short* dst = out + mat * (long)R * C;
  int c0 = blockIdx.x * 64, r0 = blockIdx.y * 64;
  int tr = threadIdx.x >> 4;
  int tc = (threadIdx.x & 15) * 4;
#pragma unroll
  for (int p = 0; p < 4; ++p) {
    int r = tr + p * 16;
    float4 v = *reinterpret_cast<const float4*>(&src[(long)(r0 + r) * C + c0 + tc]);
    tile[r][tc + 0] = v.x; tile[r][tc + 1] = v.y;
    tile[r][tc + 2] = v.z; tile[r][tc + 3] = v.w;
  }
  __syncthreads();
#pragma unroll
  for (int p = 0; p < 4; ++p) {
    int c = tr + p * 16;
    ushort4 o;
    o.x = f2bf(tile[tc + 0][c]);
    o.y = f2bf(tile[tc + 1][c]);
    o.z = f2bf(tile[tc + 2][c]);
    o.w = f2bf(tile[tc + 3][c]);
    *reinterpret_cast<ushort4*>(&dst[(long)(c0 + c) * R + r0 + tc]) = o;
  }
}

// ---------------- Kernel 3: Qm/Km = l2norm(x @ W^T), bf16x3-split MFMA --
__global__ __launch_bounds__(512) void qkm_kernel(
    const float* __restrict__ x,
    const float* __restrict__ wq,
    const float* __restrict__ wk,
    unsigned short* __restrict__ Qm,
    float* __restrict__ Km,
    unsigned short* __restrict__ Kmb) {
  const bool isK = (blockIdx.y == 1);
  const float* w = isK ? wk : wq;
  int r0 = blockIdx.x * 64;
  int wave = threadIdx.x >> 6, lane = threadIdx.x & 63;
  int wm = wave >> 2, wn = wave & 3;
  int khi = lane >> 4, l16 = lane & 15;
  __shared__ unsigned short Ahi[64 * 32], Alo[64 * 32];
  __shared__ unsigned short Bhi[256 * 32], Blo[256 * 32];
  __shared__ float red[4][64];
  f32x4 acc[2][4] = {};
  for (int k0 = 0; k0 < 512; k0 += 32) {
    {
      int row = threadIdx.x >> 3;
      int kc = (threadIdx.x & 7) * 4;
      float4 v = *reinterpret_cast<const float4*>(&x[(long)(r0 + row) * 512 + k0 + kc]);
      float vv[4] = {v.x, v.y, v.z, v.w};
      unsigned int hx[2], lx[2];
      unsigned short h0 = f2bf(vv[0]), h1 = f2bf(vv[1]), h2 = f2bf(vv[2]), h3 = f2bf(vv[3]);
      hx[0] = (unsigned)h0 | ((unsigned)h1 << 16);
      hx[1] = (unsigned)h2 | ((unsigned)h3 << 16);
      lx[0] = (unsigned)f2bf(vv[0] - bf2f(h0)) | ((unsigned)f2bf(vv[1] - bf2f(h1)) << 16);
      lx[1] = (unsigned)f2bf(vv[2] - bf2f(h2)) | ((unsigned)f2bf(vv[3] - bf2f(h3)) << 16);
      int byt = row * 64 + ((kc * 2) ^ ((row & 3) << 4));
      *reinterpret_cast<uint2*>((char*)Ahi + byt) = make_uint2(hx[0], hx[1]);
      *reinterpret_cast<uint2*>((char*)Alo + byt) = make_uint2(lx[0], lx[1]);
    }
#pragma unroll
    for (int p = 0; p < 4; ++p) {
      int idx2 = threadIdx.x + p * 512;
      int row = idx2 >> 3;
      int kc = (idx2 & 7) * 4;
      float4 v = *reinterpret_cast<const float4*>(&w[(long)row * 512 + k0 + kc]);
      float vv[4] = {v.x, v.y, v.z, v.w};
      unsigned short h0 = f2bf(vv[0]), h1 = f2bf(vv[1]), h2 = f2bf(vv[2]), h3 = f2bf(vv[3]);
      unsigned int hx0 = (unsigned)h0 | ((unsigned)h1 << 16);
      unsigned int hx1 = (unsigned)h2 | ((unsigned)h3 << 16);
      unsigned int lx0 = (unsigned)f2bf(vv[0] - bf2f(h0)) | ((unsigned)f2bf(vv[1] - bf2f(h1)) << 16);
      unsigned int lx1 = (unsigned)f2bf(vv[2] - bf2f(h2)) | ((unsigned)f2bf(vv[3] - bf2f(h3)) << 16);
      int byt = row * 64 + ((kc * 2) ^ ((row & 3) << 4));
      *reinterpret_cast<uint2*>((char*)Bhi + byt) = make_uint2(hx0, hx1);
      *reinterpret_cast<uint2*>((char*)Blo + byt) = make_uint2(lx0, lx1);
    }
    __syncthreads();
    bf16x8 ah[2], al[2], bh[4], bl[4];
#pragma unroll
    for (int mi = 0; mi < 2; ++mi) {
      int row = wm * 32 + mi * 16 + l16;
      int byt = row * 64 + ((khi * 16) ^ ((row & 3) << 4));
      ah[mi] = *reinterpret_cast<const bf16x8*>((const char*)Ahi + byt);
      al[mi] = *reinterpret_cast<const bf16x8*>((const char*)Alo + byt);
    }
#pragma unroll
    for (int ni = 0; ni < 4; ++ni) {
      int row = wn * 64 + ni * 16 + l16;
      int byt = row * 64 + ((khi * 16) ^ ((row & 3) << 4));
      bh[ni] = *reinterpret_cast<const bf16x8*>((const char*)Bhi + byt);
      bl[ni] = *reinterpret_cast<const bf16x8*>((const char*)Blo + byt);
    }
#pragma unroll
    for (int mi = 0; mi < 2; ++mi)
#pragma unroll
      for (int ni = 0; ni < 4; ++ni) {
        acc[mi][ni] = mfma16(ah[mi], bh[ni], acc[mi][ni]);
        acc[mi][ni] = mfma16(ah[mi], bl[ni], acc[mi][ni]);
        acc[mi][ni] = mfma16(al[mi], bh[ni], acc[mi][ni]);
      }
    __syncthreads();
  }
  float part[2][4];
#pragma unroll
  for (int mi = 0; mi < 2; ++mi)
#pragma unroll
    for (int r = 0; r < 4; ++r) {
      float s = 0.f;
#pragma unroll
      for (int ni = 0; ni < 4; ++ni) s += acc[mi][ni][r] * acc[mi][ni][r];
      part[mi][r] = s;
    }
#pragma unroll
  for (int off = 1; off < 16; off <<= 1)
#pragma unroll
    for (int mi = 0; mi < 2; ++mi)
#pragma unroll
      for (int r = 0; r < 4; ++r) part[mi][r] += __shfl_xor(part[mi][r], off);
  if (l16 == 0) {
#pragma unroll
    for (int mi = 0; mi < 2; ++mi)
#pragma unroll
      for (int r = 0; r < 4; ++r)
        red[wn][wm * 32 + mi * 16 + khi * 4 + r] = part[mi][r];
  }
  __syncthreads();
#pragma unroll
  for (int mi = 0; mi < 2; ++mi)
#pragma unroll
    for (int r = 0; r < 4; ++r) {
      int row = wm * 32 + mi * 16 + khi * 4 + r;
      float ss = red[0][row] + red[1][row] + red[2][row] + red[3][row];
      float scale = 1.f / fmaxf(sqrtf(ss), 1e-12f);
#pragma unroll
      for (int ni = 0; ni < 4; ++ni) {
        int col = wn * 64 + ni * 16 + l16;
        float val = acc[mi][ni][r] * scale;
        if (isK) {
          Km[(long)(r0 + row) * 256 + col] = val;
          Kmb[(long)(r0 + row) * 256 + col] = f2bf(val);
        } else {
          Qm[(long)(r0 + row) * 256 + col] = f2bf(val);
        }
      }
    }
}

// ---------------- Kernel 4: beta = sigmoid(x @ beta_w^T) ----------------
__global__ __launch_bounds__(64) void beta_kernel(const float* __restrict__ x,
                                                  const float* __restrict__ bw,
                                                  float* __restrict__ beta) {
  long row = blockIdx.x;
  int lane = threadIdx.x;
  const float* xr = x + row * 512;
  float xv[8];
#pragma unroll
  for (int j = 0; j < 8; ++j) xv[j] = xr[lane + j * 64];
#pragma unroll
  for (int hh = 0; hh < 8; ++hh) {
    const float* wr = bw + hh * 512;
    float p = 0.f;
#pragma unroll
    for (int j = 0; j < 8; ++j) p += xv[j] * wr[lane + j * 64];
#pragma unroll
    for (int off = 32; off > 0; off >>= 1) p += __shfl_down(p, off);
    if (lane == 0) beta[row * 8 + hh] = 1.f / (1.f + expf(-p));
  }
}

// ---------------- Kernel 5a: per-chunk W = (I + diag(b) L)^-1 diag(b) ---
__global__ __launch_bounds__(256) void wprep_kernel(
    const float* __restrict__ Km, const float* __restrict__ beta,
    unsigned short* __restrict__ Whi, unsigned short* __restrict__ Wlo) {
  __shared__ unsigned short Khi[64 * 256];
  __shared__ unsigned short Klo[64 * 256];
  __shared__ float Bm[64 * 64];
  __shared__ float bv[64];
  int blk = blockIdx.x, ch = blk & 31, bh = blk >> 5;
  int b = bh >> 3, h = bh & 7;
  int t0 = ch * 64;
  int tid = threadIdx.x, wave = tid >> 6, lane = tid & 63;
  int khi = lane >> 4, l16 = lane & 15;
  {
    int t = tid >> 2, n0 = (tid & 3) * 64;
    const float* kp = Km + ((long)(b * TSEQ) + t0 + t) * 256 + n0;
    char* ph = (char*)Khi + t * 512;
    char* pl = (char*)Klo + t * 512;
#pragma unroll
    for (int i = 0; i < 64; i += 8) {
      float4 v0 = *(const float4*)(kp + i);
      float4 v1 = *(const float4*)(kp + i + 4);
      float vv[8] = {v0.x, v0.y, v0.z, v0.w, v1.x, v1.y, v1.z, v1.w};
      unsigned int hw[4], lw[4];
#pragma unroll
      for (int q = 0; q < 4; ++q) {
        unsigned short h0 = f2bf(vv[2 * q]), h1 = f2bf(vv[2 * q + 1]);
        hw[q] = (unsigned)h0 | ((unsigned)h1 << 16);
        lw[q] = (unsigned)f2bf(vv[2 * q] - bf2f(h0)) |
                ((unsigned)f2bf(vv[2 * q + 1] - bf2f(h1)) << 16);
      }
      int off = ((n0 + i) * 2) ^ ((t & 7) << 4);
      *(uint4*)(ph + off) = make_uint4(hw[0], hw[1], hw[2], hw[3]);
      *(uint4*)(pl + off) = make_uint4(lw[0], lw[1], lw[2], lw[3]);
    }
  }
  if (tid < 64) bv[tid] = beta[((long)(b * TSEQ) + t0 + tid) * 8 + h];
  __syncthreads();
  f32x4 sacc[4] = {};
#pragma unroll
  for (int ks = 0; ks < 8; ++ks) {
    int arow = wave * 16 + l16;
    int koff = (ks * 32 + khi * 8) * 2;
    bf16x8 ah = *(const bf16x8*)((const char*)Khi + arow * 512 + (koff ^ ((arow & 7) << 4)));
    bf16x8 al = *(const bf16x8*)((const char*)Klo + arow * 512 + (koff ^ ((arow & 7) << 4)));
    bf16x8 bhf[4], blf[4];
#pragma unroll
    for (int si = 0; si < 4; ++si) {
      int brow = si * 16 + l16;
      bhf[si] = *(const bf16x8*)((const char*)Khi + brow * 512 + (koff ^ ((brow & 7) << 4)));
      blf[si] = *(const bf16x8*)((const char*)Klo + brow * 512 + (koff ^ ((brow & 7) << 4)));
    }
#pragma unroll
    for (int si = 0; si < 4; ++si) sacc[si] = mfma16(ah, bhf[si], sacc[si]);
#pragma unroll
    for (int si = 0; si < 4; ++si) sacc[si] = mfma16(ah, blf[si], sacc[si]);
#pragma unroll
    for (int si = 0; si < 4; ++si) sacc[si] = mfma16(al, bhf[si], sacc[si]);
  }
#pragma unroll
  for (int si = 0; si < 4; ++si)
#pragma unroll
    for (int r = 0; r < 4; ++r) {
      int t = wave * 16 + khi * 4 + r, s = si * 16 + l16;
      Bm[t * 64 + s] = (s < t) ? bv[t] * sacc[si][r] : 0.f;
    }
  __syncthreads();
  if (wave == 0) {
    float x[64];
#pragma unroll
    for (int i = 0; i < 64; ++i) x[i] = 0.f;
    long base = (long)blk * 4096;
    const f32x4* BmV = (const f32x4*)Bm;
    float bl = bv[lane];
#pragma unroll
    for (int t = 0; t < 64; ++t) {
      float p0 = 0.f, p1 = 0.f, p2 = 0.f, p3 = 0.f;
#pragma unroll
      for (int rq = 0; rq < 16; ++rq) {
        f32x4 b4 = BmV[t * 16 + rq];
        p0 = fmaf(b4.x, x[rq * 4 + 0], p0);
        p1 = fmaf(b4.y, x[rq * 4 + 1], p1);
        p2 = fmaf(b4.z, x[rq * 4 + 2], p2);
        p3 = fmaf(b4.w, x[rq * 4 + 3], p3);
      }
      float xv = ((lane == t) ? 1.f : 0.f) - ((p0 + p1) + (p2 + p3));
      x[t] = xv;
      float wv = xv * bl;
      unsigned short hi = f2bf(wv);
      Whi[base + t * 64 + lane] = hi;
      Wlo[base + t * 64 + lane] = f2bf(wv - bf2f(hi));
    }
  }
}

// ---------------- Kernel 5b: chunked scan, M in MFMA accumulators -------
__global__ __launch_bounds__(256) void cscan_kernel(
    const unsigned short* __restrict__ Kb,
    const unsigned short* __restrict__ KbT,
    const float* __restrict__ xn,
    const float* __restrict__ M0,
    const unsigned short* __restrict__ Whi,
    const unsigned short* __restrict__ Wlo,
    float* __restrict__ Mout) {
  __shared__ unsigned short Mthi[64 * 256];
  __shared__ unsigned short Mtlo[64 * 256];
  __shared__ unsigned short Kr[64 * 256];
  __shared__ unsigned short Pool[16384];
  __shared__ unsigned short RU0[64 * 64];
  __shared__ unsigned short RU1[64 * 64];
  unsigned short* Wh = Pool;
  unsigned short* Wl = Pool + 4096;
  unsigned short* Krt = Pool;
  int bh = blockIdx.x, dsl = blockIdx.y;
  int b = bh >> 3;
  int d0 = dsl * 64;
  int tid = threadIdx.x, wave = tid >> 6, lane = tid & 63;
  int khi = lane >> 4, l16 = lane & 15;
  const char* KbBase = (const char*)(Kb + (long)b * TSEQ * 256);

  f32x4 macc[4][4];
  const float* M0p = M0 + (long)bh * 256 * 512;
#pragma unroll
  for (int ni = 0; ni < 4; ++ni)
#pragma unroll
    for (int di = 0; di < 4; ++di)
#pragma unroll
      for (int r = 0; r < 4; ++r) {
        int n = wave * 64 + ni * 16 + khi * 4 + r;
        macc[ni][di][r] = M0p[(long)n * 512 + d0 + di * 16 + l16];
      }
#pragma unroll
  for (int ni = 0; ni < 4; ++ni)
#pragma unroll
    for (int di = 0; di < 4; ++di) {
      int n = wave * 64 + ni * 16 + khi * 4;
      int d = di * 16 + l16;
      unsigned short hq[4], lq[4];
#pragma unroll
      for (int r = 0; r < 4; ++r) {
        float v = macc[ni][di][r];
        hq[r] = f2bf(v); lq[r] = f2bf(v - bf2f(hq[r]));
      }
      int off = d * 512 + (((n * 2) ^ ((d & 7) << 4)));
      *(uint2*)((char*)Mthi + off) =
          make_uint2((unsigned)hq[0] | ((unsigned)hq[1] << 16),
                     (unsigned)hq[2] | ((unsigned)hq[3] << 16));
      *(uint2*)((char*)Mtlo + off) =
          make_uint2((unsigned)lq[0] | ((unsigned)lq[1] << 16),
                     (unsigned)lq[2] | ((unsigned)lq[3] << 16));
    }
#pragma unroll
  for (int q = 0; q < 8; ++q) {
    int lin = tid * 16 + q * 4096;
    int t = lin >> 9;
    int c = (lin & 511) ^ KSW(t);
    __builtin_amdgcn_global_load_lds((const g_uint*)(KbBase + (long)t * 512 + c),
                                     (lds_uint*)((char*)Kr + lin), 16, 0, 0);
  }
  __syncthreads();

  for (int ch = 0; ch < 32; ++ch) {
    int tc0 = ch * 64;
    {
      const char* whb = (const char*)(Whi + ((long)bh * 32 + ch) * 4096);
      const char* wlb = (const char*)(Wlo + ((long)bh * 32 + ch) * 4096);
#pragma unroll
      for (int q = 0; q < 2; ++q) {
        int lin = tid * 16 + q * 4096;
        int t = lin >> 7, c = lin & 127;
        int sb = t * 128 + (c ^ ((t & 7) << 4));
        __builtin_amdgcn_global_load_lds((const g_uint*)(whb + sb),
                                         (lds_uint*)((char*)Wh + lin), 16, 0, 0);
        __builtin_amdgcn_global_load_lds((const g_uint*)(wlb + sb),
                                         (lds_uint*)((char*)Wl + lin), 16, 0, 0);
      }
    }
    float vreg[4][4];
    {
      const float* vp = xn + ((long)b * TSEQ + tc0) * 512 + d0;
#pragma unroll
      for (int di = 0; di < 4; ++di)
#pragma unroll
        for (int r = 0; r < 4; ++r) {
          int t = wave * 16 + khi * 4 + r;
          vreg[di][r] = vp[(long)t * 512 + di * 16 + l16];
        }
    }
    __syncthreads();  // B1

    f32x4 aacc[4] = {};
#pragma unroll
    for (int ks = 0; ks < 8; ++ks) {
      int arow = wave * 16 + l16;
      int koff = (ks * 32 + khi * 8) * 2;
      bf16x8 af = *(const bf16x8*)((const char*)Kr + arow * 512 + (koff ^ KSW(arow)));
      bf16x8 mh[4], ml[4];
#pragma unroll
      for (int di = 0; di < 4; ++di) {
        int drow = di * 16 + l16;
        mh[di] = *(const bf16x8*)((const char*)Mthi + drow * 512 + (koff ^ ((drow & 7) << 4)));
        ml[di] = *(const bf16x8*)((const char*)Mtlo + drow * 512 + (koff ^ ((drow & 7) << 4)));
      }
#pragma unroll
      for (int di = 0; di < 4; ++di) aacc[di] = mfma16(af, mh[di], aacc[di]);
#pragma unroll
      for (int di = 0; di < 4; ++di) aacc[di] = mfma16(af, ml[di], aacc[di]);
    }
#pragma unroll
    for (int di = 0; di < 4; ++di) {
      int t = wave * 16 + khi * 4;
      int d = di * 16 + l16;
      unsigned short rq[4];
#pragma unroll
      for (int r = 0; r < 4; ++r) rq[r] = f2bf(vreg[di][r] - aacc[di][r]);
      int off = d * 128 + (((t * 2) ^ ((d & 7) << 4)));
      *(uint2*)((char*)RU0 + off) =
          make_uint2((unsigned)rq[0] | ((unsigned)rq[1] << 16),
                     (unsigned)rq[2] | ((unsigned)rq[3] << 16));
    }
    __syncthreads();  // B2

    if (ch + 1 < 32) {
      const char* kb2 = KbBase + (long)(tc0 + 64) * 512;
#pragma unroll
      for (int q = 0; q < 8; ++q) {
        int lin = tid * 16 + q * 4096;
        int t = lin >> 9;
        int c = (lin & 511) ^ KSW(t);
        __builtin_amdgcn_global_load_lds((const g_uint*)(kb2 + (long)t * 512 + c),
                                         (lds_uint*)((char*)Kr + lin), 16, 0, 0);
      }
    }

    f32x4 uacc[4] = {};
#pragma unroll
    for (int ks = 0; ks < 2; ++ks) {
      int arow = wave * 16 + l16;
      int soff = (ks * 32 + khi * 8) * 2;
      bf16x8 wh_ = *(const bf16x8*)((const char*)Wh + arow * 128 + (soff ^ ((arow & 7) << 4)));
      bf16x8 wl_ = *(const bf16x8*)((const char*)Wl + arow * 128 + (soff ^ ((arow & 7) << 4)));
      bf16x8 rf[4];
#pragma unroll
      for (int di = 0; di < 4; ++di) {
        int drow = di * 16 + l16;
        rf[di] = *(const bf16x8*)((const char*)RU0 + drow * 128 + (soff ^ ((drow & 7) << 4)));
      }
#pragma unroll
      for (int di = 0; di < 4; ++di) uacc[di] = mfma16(wh_, rf[di], uacc[di]);
#pragma unroll
      for (int di = 0; di < 4; ++di) uacc[di] = mfma16(wl_, rf[di], uacc[di]);
    }
    __syncthreads();  // B3

    {
#pragma unroll
      for (int q = 0; q < 8; ++q) {
        int lin = tid * 16 + q * 4096;
        int n = lin >> 7, c = lin & 127;
        long sb = ((long)(b * 256 + n)) * 4096 + (long)tc0 * 2 + (c ^ ((n & 7) << 4));
        __builtin_amdgcn_global_load_lds((const g_uint*)((const char*)KbT + sb),
                                         (lds_uint*)((char*)Krt + lin), 16, 0, 0);
      }
    }
#pragma unroll
    for (int di = 0; di < 4; ++di) {
      int t = wave * 16 + khi * 4;
      int d = di * 16 + l16;
      unsigned short hq[4], lq[4];
#pragma unroll
      for (int r = 0; r < 4; ++r) {
        float u = uacc[di][r];
        hq[r] = f2bf(u); lq[r] = f2bf(u - bf2f(hq[r]));
      }
      int off = d * 128 + (((t * 2) ^ ((d & 7) << 4)));
      *(uint2*)((char*)RU0 + off) =
          make_uint2((unsigned)hq[0] | ((unsigned)hq[1] << 16),
                     (unsigned)hq[2] | ((unsigned)hq[3] << 16));
      *(uint2*)((char*)RU1 + off) =
          make_uint2((unsigned)lq[0] | ((unsigned)lq[1] << 16),
                     (unsigned)lq[2] | ((unsigned)lq[3] << 16));
    }
    __syncthreads();  // B4

#pragma unroll
    for (int ks = 0; ks < 2; ++ks) {
      int toff = (ks * 32 + khi * 8) * 2;
      bf16x8 ka[4];
#pragma unroll
      for (int ni = 0; ni < 4; ++ni) {
        int n = wave * 64 + ni * 16 + l16;
        ka[ni] = *(const bf16x8*)((const char*)Krt + n * 128 + (toff ^ ((n & 7) << 4)));
      }
      bf16x8 uh[4], ul[4];
#pragma unroll
      for (int di = 0; di < 4; ++di) {
        int drow = di * 16 + l16;
        uh[di] = *(const bf16x8*)((const char*)RU0 + drow * 128 + (toff ^ ((drow & 7) << 4)));
        ul[di] = *(const bf16x8*)((const char*)RU1 + drow * 128 + (toff ^ ((drow & 7) << 4)));
      }
#pragma unroll
      for (int ni = 0; ni < 4; ++ni)
#pragma unroll
        for (int di = 0; di < 4; ++di)
          macc[ni][di] = mfma16(ka[ni], uh[di], macc[ni][di]);
#pragma unroll
      for (int ni = 0; ni < 4; ++ni)
#pragma unroll
        for (int di = 0; di < 4; ++di)
          macc[ni][di] = mfma16(ka[ni], ul[di], macc[ni][di]);
    }
#pragma unroll
    for (int ni = 0; ni < 4; ++ni)
#pragma unroll
      for (int di = 0; di < 4; ++di) {
        int n = wave * 64 + ni * 16 + khi * 4;
        int d = di * 16 + l16;
        unsigned short hq[4], lq[4];
#pragma unroll
        for (int r = 0; r < 4; ++r) {
          float v = macc[ni][di][r];
          hq[r] = f2bf(v); lq[r] = f2bf(v - bf2f(hq[r]));
        }
        int off = d * 512 + (((n * 2) ^ ((d & 7) << 4)));
        *(uint2*)((char*)Mthi + off) =
            make_uint2((unsigned)hq[0] | ((unsigned)hq[1] << 16),
                       (unsigned)hq[2] | ((unsigned)hq[3] << 16));
        *(uint2*)((char*)Mtlo + off) =
            make_uint2((unsigned)lq[0] | ((unsigned)lq[1] << 16),
                       (unsigned)lq[2] | ((unsigned)lq[3] << 16));
      }
    __syncthreads();  // B6
  }

  float* Mo = Mout + (long)bh * 256 * 512;
#pragma unroll
  for (int ni = 0; ni < 4; ++ni)
#pragma unroll
    for (int di = 0; di < 4; ++di)
#pragma unroll
      for (int r = 0; r < 4; ++r) {
        int n = wave * 64 + ni * 16 + khi * 4 + r;
        Mo[(long)n * 512 + d0 + di * 16 + l16] = macc[ni][di][r];
      }
}

// ---------------- Kernel 6: causal attention y_standard (v8) ------------
// d-split for occupancy: block = 128t x 256d, grid (32 bh, 8 bp, 2 dch),
// x = bh so all 16 blocks of a bh share one XCD's L2 (R8 locality) while
// acc[4][4]=64 VGPR (R7 body, fits 128) + 48KB LDS give 2 blocks/CU.
// QK^T duplicated across the 2 dch halves (+12us MFMA) to buy overlap.
__global__ __launch_bounds__(512, 4) void attn_kernel(
    const unsigned short* __restrict__ QR,
    const unsigned short* __restrict__ Vt,
    float* __restrict__ Y) {
  int bh = blockIdx.x;     // 0..31
  int bp = blockIdx.y;     // 0..7
  int dch = blockIdx.z;    // 0..1
  int wave = threadIdx.x >> 6, lane = threadIdx.x & 63;
  int wr = wave >> 2, wc = wave & 3;
  int khi = lane >> 4, l16 = lane & 15;
  __shared__ unsigned short K_lds[64 * 256];   // 32KB
  __shared__ unsigned short S_lds[128 * 64];   // 16KB
  const unsigned short* QRb = QR + (long)bh * TSEQ * 256;
  const unsigned short* Vtb = Vt + (long)bh * 512 * TSEQ;
  int d0 = dch * 256;
  float* yb = Y + (long)bh * TSEQ * 512;
  int lin_base = wave * 4096 + lane * 16;

#pragma unroll 1
  for (int half = 0; half < 2; ++half) {
    int bt = half ? bp : (15 - bp);
    int t0 = bt * 128;
    int nst = 2 * bt + 2;

    bf16x8 qa[8];
    {
      int trow = t0 + wave * 16 + l16;
      const unsigned short* qp = QRb + (long)trow * 256 + khi * 8;
#pragma unroll
      for (int ks = 0; ks < 8; ++ks) qa[ks] = *(const bf16x8*)(qp + ks * 32);
    }
    f32x4 acc[4][4] = {};

    // prologue: stage K tile st=0
#pragma unroll
    for (int q = 0; q < 4; ++q) {
      int linear = lin_base + q * 1024;
      int row = linear >> 9;
      int nc2 = (linear & 511) ^ ((row & 7) << 4);
      __builtin_amdgcn_global_load_lds(
          (const g_uint*)((const char*)QRb + (long)row * 512 + nc2),
          (lds_uint*)((char*)K_lds + (wave * 4 + q) * 1024), 16, 0, 0);
    }
    __syncthreads();

    for (int st = 0; st < nst; ++st) {
      int s0 = st * 64;
      // phase 1: S = Q K^T (wave -> 16 rows x 64 cols)
      f32x4 sacc[4] = {};
#pragma unroll
      for (int ks = 0; ks < 8; ++ks) {
#pragma unroll
        for (int fc = 0; fc < 4; ++fc) {
          int srow = fc * 16 + l16;
          bf16x8 kf = *(const bf16x8*)(
              (const char*)K_lds + srow * 512 + ((ks * 64 + khi * 16) ^ ((srow & 7) << 4)));
          sacc[fc] = mfma16(qa[ks], kf, sacc[fc]);
        }
      }
      // mask (strict lower) + cast + store S
#pragma unroll
      for (int fc = 0; fc < 4; ++fc)
#pragma unroll
        for (int r = 0; r < 4; ++r) {
          int srow = wave * 16 + khi * 4 + r;
          int scol = fc * 16 + l16;
          float v = ((s0 + scol) < (t0 + srow)) ? sacc[fc][r] : 0.f;
          *(unsigned short*)(
              (char*)S_lds + srow * 128 + ((scol * 2) ^ ((srow & 7) << 4))) = f2bf(v);
        }
      __syncthreads();   // S ready, K_lds phase-1 reads done

      // prefetch next K tile (async; drains at loop-end barrier)
      if (st + 1 < nst) {
        long srow_base = (long)(s0 + 64) * 512;
#pragma unroll
        for (int q = 0; q < 4; ++q) {
          int linear = lin_base + q * 1024;
          int row = linear >> 9;
          int nc2 = (linear & 511) ^ ((row & 7) << 4);
          __builtin_amdgcn_global_load_lds(
              (const g_uint*)((const char*)QRb + srow_base + (long)row * 512 + nc2),
              (lds_uint*)((char*)K_lds + (wave * 4 + q) * 1024), 16, 0, 0);
        }
      }
      // phase 2: O += S @ V  (wave tile 64t x 64d within this dch half)
#pragma unroll
      for (int k2 = 0; k2 < 2; ++k2) {
        bf16x8 af[4], bfv[4];
#pragma unroll
        for (int mi = 0; mi < 4; ++mi) {
          int row = wr * 64 + mi * 16 + l16;
          af[mi] = *(const bf16x8*)(
              (const char*)S_lds + row * 128 + ((k2 * 64 + khi * 16) ^ ((row & 7) << 4)));
        }
#pragma unroll
        for (int ni = 0; ni < 4; ++ni) {
          int d = d0 + wc * 64 + ni * 16 + l16;
          bfv[ni] = *(const bf16x8*)(Vtb + (long)d * TSEQ + s0 + k2 * 32 + khi * 8);
        }
#pragma unroll
        for (int mi = 0; mi < 4; ++mi)
#pragma unroll
          for (int ni = 0; ni < 4; ++ni)
            acc[mi][ni] = mfma16(af[mi], bfv[ni], acc[mi][ni]);
      }
      __syncthreads();   // K_lds[st+1] landed (vmcnt drain), S_lds reads done
    }

    // write Y for this half
#pragma unroll
    for (int mi = 0; mi < 4; ++mi)
#pragma unroll
      for (int ni = 0; ni < 4; ++ni)
#pragma unroll
        for (int r = 0; r < 4; ++r) {
          int trow = t0 + wr * 64 + mi * 16 + khi * 4 + r;
          int d = d0 + wc * 64 + ni * 16 + l16;
          yb[(long)trow * 512 + d] = acc[mi][ni][r];
        }
  }
}

// ---------------- Kernel 7: y_memory GEMM + LN + gated combine ----------
__global__ __launch_bounds__(512) void combine_kernel(
    const unsigned short* __restrict__ Qm,
    const unsigned short* __restrict__ M0t,
    const float* __restrict__ mg,
    float* __restrict__ Y) {
  int t0 = blockIdx.x * 64;
  int bh = blockIdx.y;
  int b = bh >> 3, h = bh & 7;
  int wv = threadIdx.x >> 6, lane = threadIdx.x & 63;
  int khi = lane >> 4, l16 = lane & 15;
  __shared__ unsigned short A_lds[64 * 256];
  __shared__ float red_s[8][64], red_q[8][64];
  __shared__ float mu_s[64], inv_s[64];
  {
    const unsigned short* src = Qm + ((long)b * TSEQ + t0) * 256;
#pragma unroll
    for (int p = 0; p < 4; ++p) {
      int row = (threadIdx.x >> 5) + p * 16;
      int nc = (threadIdx.x & 31) * 8;
      bf16x8 v = *reinterpret_cast<const bf16x8*>(src + (long)row * 256 + nc);
      *reinterpret_cast<bf16x8*>((char*)A_lds + row * 512 + ((nc * 2) ^ ((row & 7) << 4))) = v;
    }
  }
  __syncthreads();
  f32x4 acc[4][4] = {};
  const unsigned short* Bp = M0t + (long)bh * 512 * 256;
#pragma unroll
  for (int ks = 0; ks < 8; ++ks) {
    bf16x8 a[4], bfr[4];
#pragma unroll
    for (int mi = 0; mi < 4; ++mi) {
      int row = mi * 16 + l16;
      a[mi] = *reinterpret_cast<const bf16x8*>(
          (const char*)A_lds + row * 512 + ((ks * 64 + khi * 16) ^ ((row & 7) << 4)));
    }
#pragma unroll
    for (int ni = 0; ni < 4; ++ni) {
      int d = wv * 64 + ni * 16 + l16;
      bfr[ni] = *reinterpret_cast<const bf16x8*>(Bp + (long)d * 256 + ks * 32 + khi * 8);
    }
#pragma unroll
    for (int mi = 0; mi < 4; ++mi)
#pragma unroll
      for (int ni = 0; ni < 4; ++ni)
        acc[mi][ni] = mfma16(a[mi], bfr[ni], acc[mi][ni]);
  }
  float ps[4][4], pq[4][4];
#pragma unroll
  for (int mi = 0; mi < 4; ++mi)
#pragma unroll
    for (int r = 0; r < 4; ++r) {
      float s = 0.f, q = 0.f;
#pragma unroll
      for (int ni = 0; ni < 4; ++ni) {
        float v = acc[mi][ni][r];
        s += v; q += v * v;
      }
      ps[mi][r] = s; pq[mi][r] = q;
    }
#pragma unroll
  for (int off = 1; off < 16; off <<= 1)
#pragma unroll
    for (int mi = 0; mi < 4; ++mi)
#pragma unroll
      for (int r = 0; r < 4; ++r) {
        ps[mi][r] += __shfl_xor(ps[mi][r], off);
        pq[mi][r] += __shfl_xor(pq[mi][r], off);
      }
  if (l16 == 0) {
#pragma unroll
    for (int mi = 0; mi < 4; ++mi)
#pragma unroll
      for (int r = 0; r < 4; ++r) {
        int row = mi * 16 + khi * 4 + r;
        red_s[wv][row] = ps[mi][r];
        red_q[wv][row] = pq[mi][r];
      }
  }
  __syncthreads();
  if (threadIdx.x < 64) {
    float s = 0.f, q = 0.f;
#pragma unroll
    for (int w2 = 0; w2 < 8; ++w2) { s += red_s[w2][threadIdx.x]; q += red_q[w2][threadIdx.x]; }
    float mu = s / 512.f;
    float var = q / 512.f - mu * mu;
    mu_s[threadIdx.x] = mu;
    inv_s[threadIdx.x] = rsqrtf(var + 1e-5f);
  }
  __syncthreads();
  float gate = 1.f / (1.f + expf(-mg[h]));
  float omg = 1.f - gate;
  float* yb = Y + ((long)bh * TSEQ + t0) * 512;
#pragma unroll
  for (int mi = 0; mi < 4; ++mi)
#pragma unroll
    for (int r = 0; r < 4; ++r) {
      int row = mi * 16 + khi * 4 + r;
      float mu = mu_s[row], inv = inv_s[row];
#pragma unroll
      for (int ni = 0; ni < 4; ++ni) {
        int d = wv * 64 + ni * 16 + l16;
        long off = (long)row * 512 + d;
        float ymv = (acc[mi][ni][r] - mu) * inv;
        yb[off] = omg * yb[off] + gate * ymv;
      }
    }
}

// ---------------- host launcher -----------------------------------------
extern "C" void kernel_launch(void* const* d_in, const int* in_sizes, int n_in,
                              void* d_out, int out_size, void* d_ws, size_t ws_size,
                              hipStream_t stream) {
  const float* Q      = (const float*)d_in[0];
  const float* V      = (const float*)d_in[1];
  const float* x_raw  = (const float*)d_in[2];
  const float* x_next = (const float*)d_in[3];
  const float* wq     = (const float*)d_in[4];
  const float* wk     = (const float*)d_in[5];
  const float* bw     = (const float*)d_in[6];
  const float* mg     = (const float*)d_in[7];
  const float* M0     = (const float*)d_in[8];
  float* y = (float*)d_out;
  float* Mout = y + (long)32 * 2048 * 512;

  char* ws = (char*)d_ws;
  unsigned short* QR  = (unsigned short*)(ws);                 // 33,554,432 B
  unsigned short* Vt  = (unsigned short*)(ws + 33554432);      // 67,108,864 B
  unsigned short* M0t = (unsigned short*)(ws + 100663296);     //  8,388,608 B
  unsigned short* Qm  = (unsigned short*)(ws + 109051904);     //  4,194,304 B
  float*  Km          = (float*)(ws + 113246208);              //  8,388,608 B
  float*  beta        = (float*)(ws + 121634816);              //    262,144 B
  // Aliased inside the Vt region (all consumed before transposeV writes Vt):
  unsigned short* Whi = (unsigned short*)(ws + 33554432);      //  8,388,608 B
  unsigned short* Wlo = (unsigned short*)(ws + 41943040);      //  8,388,608 B
  unsigned short* Kmb = (unsigned short*)(ws + 50331648);      //  4,194,304 B
  unsigned short* KmT = (unsigned short*)(ws + 54525952);      //  4,194,304 B

  qkm_kernel<<<dim3(128, 2), dim3(512), 0, stream>>>(x_raw, wq, wk, Qm, Km, Kmb);
  transpose_cast_kernel<<<dim3(4, 32, 4), dim3(256), 0, stream>>>(Km, KmT, 2048, 256);
  beta_kernel<<<dim3(8192), dim3(64), 0, stream>>>(x_raw, bw, beta);
  wprep_kernel<<<dim3(1024), dim3(256), 0, stream>>>(Km, beta, Whi, Wlo);
  cscan_kernel<<<dim3(32, 8), dim3(256), 0, stream>>>(Kmb, KmT, x_next, M0, Whi, Wlo, Mout);
  rope_kernel<<<dim3(32768), dim3(256), 0, stream>>>(Q, QR);
  transpose_cast_kernel<<<dim3(8, 32, 32), dim3(256), 0, stream>>>(V, Vt, 2048, 512);
  transpose_cast_kernel<<<dim3(8, 4, 32), dim3(256), 0, stream>>>(M0, M0t, 256, 512);
  attn_kernel<<<dim3(32, 8, 2), dim3(512), 0, stream>>>(QR, Vt, y);
  combine_kernel<<<dim3(32, 32), dim3(512), 0, stream>>>(Qm, M0t, mg, y);
}

// Round 14
// 705.933 us; speedup vs baseline: 1.4285x; 1.4285x over previous
//
#include <hip/hip_runtime.h>
#include <hip/hip_bf16.h>
#include <math.h>

#define BBATCH 4
#define NHEAD  8
#define TSEQ   2048
#define NDIM   256
#define DDIM   512

typedef float f32x4 __attribute__((ext_vector_type(4)));
typedef short bf16x8 __attribute__((ext_vector_type(8)));

typedef __attribute__((address_space(3))) unsigned int lds_uint;
typedef __attribute__((address_space(1))) unsigned int g_uint;

__device__ __forceinline__ unsigned short f2bf(float f) {
  __hip_bfloat16 h = __float2bfloat16(f);
  return *reinterpret_cast<unsigned short*>(&h);
}
__device__ __forceinline__ float bf2f(unsigned short u) {
  __hip_bfloat16 h;
  *reinterpret_cast<unsigned short*>(&h) = u;
  return __bfloat162float(h);
}
__device__ __forceinline__ f32x4 mfma16(bf16x8 a, bf16x8 b, f32x4 c) {
  return __builtin_amdgcn_mfma_f32_16x16x32_bf16(a, b, c, 0, 0, 0);
}

// Kr swizzle (two-level, spreads both row-low and row-mid bits)
#define KSW(t) (((((t) & 7) ^ (((t) >> 3) & 3))) << 4)

// ---------------- Kernel 1: RoPE(Q) -> QR bf16 --------------------------
__global__ __launch_bounds__(256) void rope_kernel(const float* __restrict__ Q,
                                                   unsigned short* __restrict__ QR) {
  long idx = (long)blockIdx.x * 256 + threadIdx.x;
  int pair = (int)(idx & 127);
  long row = idx >> 7;
  int t = (int)(row & (TSEQ - 1));
  float2 q = reinterpret_cast<const float2*>(Q)[idx];
  float freq = exp2f(-(float)pair * 0.125f) * 0.15915494309189535f;
  float phase = (float)t * freq;
  float ph = (phase - floorf(phase)) * 6.283185307179586f;
  float s, c;
  sincosf(ph, &s, &c);
  float o0 = q.x * c - q.y * s;
  float o1 = q.y * c + q.x * s;
  unsigned int pk = (unsigned int)f2bf(o0) | ((unsigned int)f2bf(o1) << 16);
  reinterpret_cast<unsigned int*>(QR)[idx] = pk;
}

// ---------------- Kernel 2: transpose + cast f32[R][C] -> bf16[C][R] ----
__global__ __launch_bounds__(256) void transpose_cast_kernel(
    const float* __restrict__ in, unsigned short* __restrict__ out, int R, int C) {
  __shared__ float tile[64][65];
  long mat = blockIdx.z;
  const float* src = in + mat * (long)R * C;
  unsigned short* dst = out + mat * (long)R * C;
  int c0 = blockIdx.x * 64, r0 = blockIdx.y * 64;
  int tr = threadIdx.x >> 4;
  int tc = (threadIdx.x & 15) * 4;
#pragma unroll
  for (int p = 0; p < 4; ++p) {
    int r = tr + p * 16;
    float4 v = *reinterpret_cast<const float4*>(&src[(long)(r0 + r) * C + c0 + tc]);
    tile[r][tc + 0] = v.x; tile[r][tc + 1] = v.y;
    tile[r][tc + 2] = v.z; tile[r][tc + 3] = v.w;
  }
  __syncthreads();
#pragma unroll
  for (int p = 0; p < 4; ++p) {
    int c = tr + p * 16;
    ushort4 o;
    o.x = f2bf(tile[tc + 0][c]);
    o.y = f2bf(tile[tc + 1][c]);
    o.z = f2bf(tile[tc + 2][c]);
    o.w = f2bf(tile[tc + 3][c]);
    *reinterpret_cast<ushort4*>(&dst[(long)(c0 + c) * R + r0 + tc]) = o;
  }
}

// ---------------- Kernel 3: Qm/Km = l2norm(x @ W^T), bf16x3-split MFMA --
__global__ __launch_bounds__(512) void qkm_kernel(
    const float* __restrict__ x,
    const float* __restrict__ wq,
    const float* __restrict__ wk,
    unsigned short* __restrict__ Qm,
    float* __restrict__ Km,
    unsigned short* __restrict__ Kmb) {
  const bool isK = (blockIdx.y == 1);
  const float* w = isK ? wk : wq;
  int r0 = blockIdx.x * 64;
  int wave = threadIdx.x >> 6, lane = threadIdx.x & 63;
  int wm = wave >> 2, wn = wave & 3;
  int khi = lane >> 4, l16 = lane & 15;
  __shared__ unsigned short Ahi[64 * 32], Alo[64 * 32];
  __shared__ unsigned short Bhi[256 * 32], Blo[256 * 32];
  __shared__ float red[4][64];
  f32x4 acc[2][4] = {};
  for (int k0 = 0; k0 < 512; k0 += 32) {
    {
      int row = threadIdx.x >> 3;
      int kc = (threadIdx.x & 7) * 4;
      float4 v = *reinterpret_cast<const float4*>(&x[(long)(r0 + row) * 512 + k0 + kc]);
      float vv[4] = {v.x, v.y, v.z, v.w};
      unsigned int hx[2], lx[2];
      unsigned short h0 = f2bf(vv[0]), h1 = f2bf(vv[1]), h2 = f2bf(vv[2]), h3 = f2bf(vv[3]);
      hx[0] = (unsigned)h0 | ((unsigned)h1 << 16);
      hx[1] = (unsigned)h2 | ((unsigned)h3 << 16);
      lx[0] = (unsigned)f2bf(vv[0] - bf2f(h0)) | ((unsigned)f2bf(vv[1] - bf2f(h1)) << 16);
      lx[1] = (unsigned)f2bf(vv[2] - bf2f(h2)) | ((unsigned)f2bf(vv[3] - bf2f(h3)) << 16);
      int byt = row * 64 + ((kc * 2) ^ ((row & 3) << 4));
      *reinterpret_cast<uint2*>((char*)Ahi + byt) = make_uint2(hx[0], hx[1]);
      *reinterpret_cast<uint2*>((char*)Alo + byt) = make_uint2(lx[0], lx[1]);
    }
#pragma unroll
    for (int p = 0; p < 4; ++p) {
      int idx2 = threadIdx.x + p * 512;
      int row = idx2 >> 3;
      int kc = (idx2 & 7) * 4;
      float4 v = *reinterpret_cast<const float4*>(&w[(long)row * 512 + k0 + kc]);
      float vv[4] = {v.x, v.y, v.z, v.w};
      unsigned short h0 = f2bf(vv[0]), h1 = f2bf(vv[1]), h2 = f2bf(vv[2]), h3 = f2bf(vv[3]);
      unsigned int hx0 = (unsigned)h0 | ((unsigned)h1 << 16);
      unsigned int hx1 = (unsigned)h2 | ((unsigned)h3 << 16);
      unsigned int lx0 = (unsigned)f2bf(vv[0] - bf2f(h0)) | ((unsigned)f2bf(vv[1] - bf2f(h1)) << 16);
      unsigned int lx1 = (unsigned)f2bf(vv[2] - bf2f(h2)) | ((unsigned)f2bf(vv[3] - bf2f(h3)) << 16);
      int byt = row * 64 + ((kc * 2) ^ ((row & 3) << 4));
      *reinterpret_cast<uint2*>((char*)Bhi + byt) = make_uint2(hx0, hx1);
      *reinterpret_cast<uint2*>((char*)Blo + byt) = make_uint2(lx0, lx1);
    }
    __syncthreads();
    bf16x8 ah[2], al[2], bh[4], bl[4];
#pragma unroll
    for (int mi = 0; mi < 2; ++mi) {
      int row = wm * 32 + mi * 16 + l16;
      int byt = row * 64 + ((khi * 16) ^ ((row & 3) << 4));
      ah[mi] = *reinterpret_cast<const bf16x8*>((const char*)Ahi + byt);
      al[mi] = *reinterpret_cast<const bf16x8*>((const char*)Alo + byt);
    }
#pragma unroll
    for (int ni = 0; ni < 4; ++ni) {
      int row = wn * 64 + ni * 16 + l16;
      int byt = row * 64 + ((khi * 16) ^ ((row & 3) << 4));
      bh[ni] = *reinterpret_cast<const bf16x8*>((const char*)Bhi + byt);
      bl[ni] = *reinterpret_cast<const bf16x8*>((const char*)Blo + byt);
    }
#pragma unroll
    for (int mi = 0; mi < 2; ++mi)
#pragma unroll
      for (int ni = 0; ni < 4; ++ni) {
        acc[mi][ni] = mfma16(ah[mi], bh[ni], acc[mi][ni]);
        acc[mi][ni] = mfma16(ah[mi], bl[ni], acc[mi][ni]);
        acc[mi][ni] = mfma16(al[mi], bh[ni], acc[mi][ni]);
      }
    __syncthreads();
  }
  float part[2][4];
#pragma unroll
  for (int mi = 0; mi < 2; ++mi)
#pragma unroll
    for (int r = 0; r < 4; ++r) {
      float s = 0.f;
#pragma unroll
      for (int ni = 0; ni < 4; ++ni) s += acc[mi][ni][r] * acc[mi][ni][r];
      part[mi][r] = s;
    }
#pragma unroll
  for (int off = 1; off < 16; off <<= 1)
#pragma unroll
    for (int mi = 0; mi < 2; ++mi)
#pragma unroll
      for (int r = 0; r < 4; ++r) part[mi][r] += __shfl_xor(part[mi][r], off);
  if (l16 == 0) {
#pragma unroll
    for (int mi = 0; mi < 2; ++mi)
#pragma unroll
      for (int r = 0; r < 4; ++r)
        red[wn][wm * 32 + mi * 16 + khi * 4 + r] = part[mi][r];
  }
  __syncthreads();
#pragma unroll
  for (int mi = 0; mi < 2; ++mi)
#pragma unroll
    for (int r = 0; r < 4; ++r) {
      int row = wm * 32 + mi * 16 + khi * 4 + r;
      float ss = red[0][row] + red[1][row] + red[2][row] + red[3][row];
      float scale = 1.f / fmaxf(sqrtf(ss), 1e-12f);
#pragma unroll
      for (int ni = 0; ni < 4; ++ni) {
        int col = wn * 64 + ni * 16 + l16;
        float val = acc[mi][ni][r] * scale;
        if (isK) {
          Km[(long)(r0 + row) * 256 + col] = val;
          Kmb[(long)(r0 + row) * 256 + col] = f2bf(val);
        } else {
          Qm[(long)(r0 + row) * 256 + col] = f2bf(val);
        }
      }
    }
}

// ---------------- Kernel 4: beta = sigmoid(x @ beta_w^T) ----------------
__global__ __launch_bounds__(64) void beta_kernel(const float* __restrict__ x,
                                                  const float* __restrict__ bw,
                                                  float* __restrict__ beta) {
  long row = blockIdx.x;
  int lane = threadIdx.x;
  const float* xr = x + row * 512;
  float xv[8];
#pragma unroll
  for (int j = 0; j < 8; ++j) xv[j] = xr[lane + j * 64];
#pragma unroll
  for (int hh = 0; hh < 8; ++hh) {
    const float* wr = bw + hh * 512;
    float p = 0.f;
#pragma unroll
    for (int j = 0; j < 8; ++j) p += xv[j] * wr[lane + j * 64];
#pragma unroll
    for (int off = 32; off > 0; off >>= 1) p += __shfl_down(p, off);
    if (lane == 0) beta[row * 8 + hh] = 1.f / (1.f + expf(-p));
  }
}

// ---------------- Kernel 5a: per-chunk W = (I + diag(b) L)^-1 diag(b) ---
__global__ __launch_bounds__(256) void wprep_kernel(
    const float* __restrict__ Km, const float* __restrict__ beta,
    unsigned short* __restrict__ Whi, unsigned short* __restrict__ Wlo) {
  __shared__ unsigned short Khi[64 * 256];
  __shared__ unsigned short Klo[64 * 256];
  __shared__ float Bm[64 * 64];
  __shared__ float bv[64];
  int blk = blockIdx.x, ch = blk & 31, bh = blk >> 5;
  int b = bh >> 3, h = bh & 7;
  int t0 = ch * 64;
  int tid = threadIdx.x, wave = tid >> 6, lane = tid & 63;
  int khi = lane >> 4, l16 = lane & 15;
  {
    int t = tid >> 2, n0 = (tid & 3) * 64;
    const float* kp = Km + ((long)(b * TSEQ) + t0 + t) * 256 + n0;
    char* ph = (char*)Khi + t * 512;
    char* pl = (char*)Klo + t * 512;
#pragma unroll
    for (int i = 0; i < 64; i += 8) {
      float4 v0 = *(const float4*)(kp + i);
      float4 v1 = *(const float4*)(kp + i + 4);
      float vv[8] = {v0.x, v0.y, v0.z, v0.w, v1.x, v1.y, v1.z, v1.w};
      unsigned int hw[4], lw[4];
#pragma unroll
      for (int q = 0; q < 4; ++q) {
        unsigned short h0 = f2bf(vv[2 * q]), h1 = f2bf(vv[2 * q + 1]);
        hw[q] = (unsigned)h0 | ((unsigned)h1 << 16);
        lw[q] = (unsigned)f2bf(vv[2 * q] - bf2f(h0)) |
                ((unsigned)f2bf(vv[2 * q + 1] - bf2f(h1)) << 16);
      }
      int off = ((n0 + i) * 2) ^ ((t & 7) << 4);
      *(uint4*)(ph + off) = make_uint4(hw[0], hw[1], hw[2], hw[3]);
      *(uint4*)(pl + off) = make_uint4(lw[0], lw[1], lw[2], lw[3]);
    }
  }
  if (tid < 64) bv[tid] = beta[((long)(b * TSEQ) + t0 + tid) * 8 + h];
  __syncthreads();
  f32x4 sacc[4] = {};
#pragma unroll
  for (int ks = 0; ks < 8; ++ks) {
    int arow = wave * 16 + l16;
    int koff = (ks * 32 + khi * 8) * 2;
    bf16x8 ah = *(const bf16x8*)((const char*)Khi + arow * 512 + (koff ^ ((arow & 7) << 4)));
    bf16x8 al = *(const bf16x8*)((const char*)Klo + arow * 512 + (koff ^ ((arow & 7) << 4)));
    bf16x8 bhf[4], blf[4];
#pragma unroll
    for (int si = 0; si < 4; ++si) {
      int brow = si * 16 + l16;
      bhf[si] = *(const bf16x8*)((const char*)Khi + brow * 512 + (koff ^ ((brow & 7) << 4)));
      blf[si] = *(const bf16x8*)((const char*)Klo + brow * 512 + (koff ^ ((brow & 7) << 4)));
    }
#pragma unroll
    for (int si = 0; si < 4; ++si) sacc[si] = mfma16(ah, bhf[si], sacc[si]);
#pragma unroll
    for (int si = 0; si < 4; ++si) sacc[si] = mfma16(ah, blf[si], sacc[si]);
#pragma unroll
    for (int si = 0; si < 4; ++si) sacc[si] = mfma16(al, bhf[si], sacc[si]);
  }
#pragma unroll
  for (int si = 0; si < 4; ++si)
#pragma unroll
    for (int r = 0; r < 4; ++r) {
      int t = wave * 16 + khi * 4 + r, s = si * 16 + l16;
      Bm[t * 64 + s] = (s < t) ? bv[t] * sacc[si][r] : 0.f;
    }
  __syncthreads();
  if (wave == 0) {
    float x[64];
#pragma unroll
    for (int i = 0; i < 64; ++i) x[i] = 0.f;
    long base = (long)blk * 4096;
    const f32x4* BmV = (const f32x4*)Bm;
    float bl = bv[lane];
#pragma unroll
    for (int t = 0; t < 64; ++t) {
      float p0 = 0.f, p1 = 0.f, p2 = 0.f, p3 = 0.f;
#pragma unroll
      for (int rq = 0; rq < 16; ++rq) {
        f32x4 b4 = BmV[t * 16 + rq];
        p0 = fmaf(b4.x, x[rq * 4 + 0], p0);
        p1 = fmaf(b4.y, x[rq * 4 + 1], p1);
        p2 = fmaf(b4.z, x[rq * 4 + 2], p2);
        p3 = fmaf(b4.w, x[rq * 4 + 3], p3);
      }
      float xv = ((lane == t) ? 1.f : 0.f) - ((p0 + p1) + (p2 + p3));
      x[t] = xv;
      float wv = xv * bl;
      unsigned short hi = f2bf(wv);
      Whi[base + t * 64 + lane] = hi;
      Wlo[base + t * 64 + lane] = f2bf(wv - bf2f(hi));
    }
  }
}

// ---------------- Kernel 5b: chunked scan (v2: 8 waves / 512 threads) ---
// Same math/LDS/barriers as before; per-wave work halved and 2 waves/SIMD
// so LDS/MFMA latency chains overlap across waves.
// A/R/U phases: wave = (tq = wave&3 -> 16t, dh = wave>>2 -> 32d half).
// M-update/Mt phases: wave owns 32 n-rows.
__global__ __launch_bounds__(512) void cscan_kernel(
    const unsigned short* __restrict__ Kb,
    const unsigned short* __restrict__ KbT,
    const float* __restrict__ xn,
    const float* __restrict__ M0,
    const unsigned short* __restrict__ Whi,
    const unsigned short* __restrict__ Wlo,
    float* __restrict__ Mout) {
  __shared__ unsigned short Mthi[64 * 256];
  __shared__ unsigned short Mtlo[64 * 256];
  __shared__ unsigned short Kr[64 * 256];
  __shared__ unsigned short Pool[16384];
  __shared__ unsigned short RU0[64 * 64];
  __shared__ unsigned short RU1[64 * 64];
  unsigned short* Wh = Pool;
  unsigned short* Wl = Pool + 4096;
  unsigned short* Krt = Pool;
  int bh = blockIdx.x, dsl = blockIdx.y;
  int b = bh >> 3;
  int d0 = dsl * 64;
  int tid = threadIdx.x, wave = tid >> 6, lane = tid & 63;
  int khi = lane >> 4, l16 = lane & 15;
  int tq = wave & 3, dh = wave >> 2;   // A/R/U split
  const char* KbBase = (const char*)(Kb + (long)b * TSEQ * 256);

  // M accumulators: wave owns n in [wave*32, wave*32+32): 2 n-tiles x 4 d-tiles
  f32x4 macc[2][4];
  const float* M0p = M0 + (long)bh * 256 * 512;
#pragma unroll
  for (int ni = 0; ni < 2; ++ni)
#pragma unroll
    for (int di = 0; di < 4; ++di)
#pragma unroll
      for (int r = 0; r < 4; ++r) {
        int n = wave * 32 + ni * 16 + khi * 4 + r;
        macc[ni][di][r] = M0p[(long)n * 512 + d0 + di * 16 + l16];
      }
#pragma unroll
  for (int ni = 0; ni < 2; ++ni)
#pragma unroll
    for (int di = 0; di < 4; ++di) {
      int n = wave * 32 + ni * 16 + khi * 4;
      int d = di * 16 + l16;
      unsigned short hq[4], lq[4];
#pragma unroll
      for (int r = 0; r < 4; ++r) {
        float v = macc[ni][di][r];
        hq[r] = f2bf(v); lq[r] = f2bf(v - bf2f(hq[r]));
      }
      int off = d * 512 + (((n * 2) ^ ((d & 7) << 4)));
      *(uint2*)((char*)Mthi + off) =
          make_uint2((unsigned)hq[0] | ((unsigned)hq[1] << 16),
                     (unsigned)hq[2] | ((unsigned)hq[3] << 16));
      *(uint2*)((char*)Mtlo + off) =
          make_uint2((unsigned)lq[0] | ((unsigned)lq[1] << 16),
                     (unsigned)lq[2] | ((unsigned)lq[3] << 16));
    }
  // prologue: stage Kr(ch=0)
#pragma unroll
  for (int q = 0; q < 4; ++q) {
    int lin = tid * 16 + q * 8192;
    int t = lin >> 9;
    int c = (lin & 511) ^ KSW(t);
    __builtin_amdgcn_global_load_lds((const g_uint*)(KbBase + (long)t * 512 + c),
                                     (lds_uint*)((char*)Kr + lin), 16, 0, 0);
  }
  __syncthreads();

  for (int ch = 0; ch < 32; ++ch) {
    int tc0 = ch * 64;
    // stage W(ch) into Pool (8KB each -> one 16B issue per thread)
    {
      const char* whb = (const char*)(Whi + ((long)bh * 32 + ch) * 4096);
      const char* wlb = (const char*)(Wlo + ((long)bh * 32 + ch) * 4096);
      int lin = tid * 16;
      int t = lin >> 7, c = lin & 127;
      int sb = t * 128 + (c ^ ((t & 7) << 4));
      __builtin_amdgcn_global_load_lds((const g_uint*)(whb + sb),
                                       (lds_uint*)((char*)Wh + lin), 16, 0, 0);
      __builtin_amdgcn_global_load_lds((const g_uint*)(wlb + sb),
                                       (lds_uint*)((char*)Wl + lin), 16, 0, 0);
    }
    // V -> regs (for this wave's R positions)
    float vreg[2][4];
    {
      const float* vp = xn + ((long)b * TSEQ + tc0) * 512 + d0;
#pragma unroll
      for (int di = 0; di < 2; ++di)
#pragma unroll
        for (int r = 0; r < 4; ++r) {
          int t = tq * 16 + khi * 4 + r;
          vreg[di][r] = vp[(long)t * 512 + (dh * 2 + di) * 16 + l16];
        }
    }
    __syncthreads();  // B1: Kr(ch), W(ch) landed

    // A = Kr * (Mthi + Mtlo): wave tile 16t x 32d
    f32x4 aacc[2] = {};
#pragma unroll
    for (int ks = 0; ks < 8; ++ks) {
      int arow = tq * 16 + l16;
      int koff = (ks * 32 + khi * 8) * 2;
      bf16x8 af = *(const bf16x8*)((const char*)Kr + arow * 512 + (koff ^ KSW(arow)));
      bf16x8 mh[2], ml[2];
#pragma unroll
      for (int di = 0; di < 2; ++di) {
        int drow = (dh * 2 + di) * 16 + l16;
        mh[di] = *(const bf16x8*)((const char*)Mthi + drow * 512 + (koff ^ ((drow & 7) << 4)));
        ml[di] = *(const bf16x8*)((const char*)Mtlo + drow * 512 + (koff ^ ((drow & 7) << 4)));
      }
#pragma unroll
      for (int di = 0; di < 2; ++di) aacc[di] = mfma16(af, mh[di], aacc[di]);
#pragma unroll
      for (int di = 0; di < 2; ++di) aacc[di] = mfma16(af, ml[di], aacc[di]);
    }
    // R = V - A -> RU0
#pragma unroll
    for (int di = 0; di < 2; ++di) {
      int t = tq * 16 + khi * 4;
      int d = (dh * 2 + di) * 16 + l16;
      unsigned short rq[4];
#pragma unroll
      for (int r = 0; r < 4; ++r) rq[r] = f2bf(vreg[di][r] - aacc[di][r]);
      int off = d * 128 + (((t * 2) ^ ((d & 7) << 4)));
      *(uint2*)((char*)RU0 + off) =
          make_uint2((unsigned)rq[0] | ((unsigned)rq[1] << 16),
                     (unsigned)rq[2] | ((unsigned)rq[3] << 16));
    }
    __syncthreads();  // B2: R visible; Kr reads done

    // prefetch Kr(ch+1)
    if (ch + 1 < 32) {
      const char* kb2 = KbBase + (long)(tc0 + 64) * 512;
#pragma unroll
      for (int q = 0; q < 4; ++q) {
        int lin = tid * 16 + q * 8192;
        int t = lin >> 9;
        int c = (lin & 511) ^ KSW(t);
        __builtin_amdgcn_global_load_lds((const g_uint*)(kb2 + (long)t * 512 + c),
                                         (lds_uint*)((char*)Kr + lin), 16, 0, 0);
      }
    }

    // U = (Wh + Wl) * R: wave tile 16t x 32d
    f32x4 uacc[2] = {};
#pragma unroll
    for (int ks = 0; ks < 2; ++ks) {
      int arow = tq * 16 + l16;
      int soff = (ks * 32 + khi * 8) * 2;
      bf16x8 wh_ = *(const bf16x8*)((const char*)Wh + arow * 128 + (soff ^ ((arow & 7) << 4)));
      bf16x8 wl_ = *(const bf16x8*)((const char*)Wl + arow * 128 + (soff ^ ((arow & 7) << 4)));
      bf16x8 rf[2];
#pragma unroll
      for (int di = 0; di < 2; ++di) {
        int drow = (dh * 2 + di) * 16 + l16;
        rf[di] = *(const bf16x8*)((const char*)RU0 + drow * 128 + (soff ^ ((drow & 7) << 4)));
      }
#pragma unroll
      for (int di = 0; di < 2; ++di) uacc[di] = mfma16(wh_, rf[di], uacc[di]);
#pragma unroll
      for (int di = 0; di < 2; ++di) uacc[di] = mfma16(wl_, rf[di], uacc[di]);
    }
    __syncthreads();  // B3: W reads done -> Pool free

    // prefetch Krt(ch) into Pool (overlays Wh/Wl)
    {
#pragma unroll
      for (int q = 0; q < 4; ++q) {
        int lin = tid * 16 + q * 8192;
        int n = lin >> 7, c = lin & 127;
        long sb = ((long)(b * 256 + n)) * 4096 + (long)tc0 * 2 + (c ^ ((n & 7) << 4));
        __builtin_amdgcn_global_load_lds((const g_uint*)((const char*)KbT + sb),
                                         (lds_uint*)((char*)Krt + lin), 16, 0, 0);
      }
    }
    // write U hi/lo
#pragma unroll
    for (int di = 0; di < 2; ++di) {
      int t = tq * 16 + khi * 4;
      int d = (dh * 2 + di) * 16 + l16;
      unsigned short hq[4], lq[4];
#pragma unroll
      for (int r = 0; r < 4; ++r) {
        float u = uacc[di][r];
        hq[r] = f2bf(u); lq[r] = f2bf(u - bf2f(hq[r]));
      }
      int off = d * 128 + (((t * 2) ^ ((d & 7) << 4)));
      *(uint2*)((char*)RU0 + off) =
          make_uint2((unsigned)hq[0] | ((unsigned)hq[1] << 16),
                     (unsigned)hq[2] | ((unsigned)hq[3] << 16));
      *(uint2*)((char*)RU1 + off) =
          make_uint2((unsigned)lq[0] | ((unsigned)lq[1] << 16),
                     (unsigned)lq[2] | ((unsigned)lq[3] << 16));
    }
    __syncthreads();  // B4: Krt landed, U visible

    // M += Krt^T-read * (Uhi + Ulo): wave owns 32 n-rows
#pragma unroll
    for (int ks = 0; ks < 2; ++ks) {
      int toff = (ks * 32 + khi * 8) * 2;
      bf16x8 ka[2];
#pragma unroll
      for (int ni = 0; ni < 2; ++ni) {
        int n = wave * 32 + ni * 16 + l16;
        ka[ni] = *(const bf16x8*)((const char*)Krt + n * 128 + (toff ^ ((n & 7) << 4)));
      }
      bf16x8 uh[4], ul[4];
#pragma unroll
      for (int di = 0; di < 4; ++di) {
        int drow = di * 16 + l16;
        uh[di] = *(const bf16x8*)((const char*)RU0 + drow * 128 + (toff ^ ((drow & 7) << 4)));
        ul[di] = *(const bf16x8*)((const char*)RU1 + drow * 128 + (toff ^ ((drow & 7) << 4)));
      }
#pragma unroll
      for (int ni = 0; ni < 2; ++ni)
#pragma unroll
        for (int di = 0; di < 4; ++di)
          macc[ni][di] = mfma16(ka[ni], uh[di], macc[ni][di]);
#pragma unroll
      for (int ni = 0; ni < 2; ++ni)
#pragma unroll
        for (int di = 0; di < 4; ++di)
          macc[ni][di] = mfma16(ka[ni], ul[di], macc[ni][di]);
    }
    // Mt rewrite (disjoint buffers from the MFMA reads above)
#pragma unroll
    for (int ni = 0; ni < 2; ++ni)
#pragma unroll
      for (int di = 0; di < 4; ++di) {
        int n = wave * 32 + ni * 16 + khi * 4;
        int d = di * 16 + l16;
        unsigned short hq[4], lq[4];
#pragma unroll
        for (int r = 0; r < 4; ++r) {
          float v = macc[ni][di][r];
          hq[r] = f2bf(v); lq[r] = f2bf(v - bf2f(hq[r]));
        }
        int off = d * 512 + (((n * 2) ^ ((d & 7) << 4)));
        *(uint2*)((char*)Mthi + off) =
            make_uint2((unsigned)hq[0] | ((unsigned)hq[1] << 16),
                       (unsigned)hq[2] | ((unsigned)hq[3] << 16));
        *(uint2*)((char*)Mtlo + off) =
            make_uint2((unsigned)lq[0] | ((unsigned)lq[1] << 16),
                       (unsigned)lq[2] | ((unsigned)lq[3] << 16));
      }
    __syncthreads();  // B6: Mt ready for next chunk
  }

  float* Mo = Mout + (long)bh * 256 * 512;
#pragma unroll
  for (int ni = 0; ni < 2; ++ni)
#pragma unroll
    for (int di = 0; di < 4; ++di)
#pragma unroll
      for (int r = 0; r < 4; ++r) {
        int n = wave * 32 + ni * 16 + khi * 4 + r;
        Mo[(long)n * 512 + d0 + di * 16 + l16] = macc[ni][di][r];
      }
}

// ---------------- Kernel 6: causal attention y_standard (v7) ------------
// R8 structure (t=128, grid(32,8), bt pairing, 2 barriers/iter) + K_lds
// double-buffered (neutral but kept; 268us measured, low FETCH).
__global__ __launch_bounds__(512) void attn_kernel(
    const unsigned short* __restrict__ QR,
    const unsigned short* __restrict__ Vt,
    float* __restrict__ Y) {
  int bh = blockIdx.x;     // 0..31
  int bp = blockIdx.y;     // 0..7
  int wave = threadIdx.x >> 6, lane = threadIdx.x & 63;
  int wr = wave >> 2, wc = wave & 3;
  int khi = lane >> 4, l16 = lane & 15;
  __shared__ unsigned short K_lds[2][64 * 256];  // 2 x 32KB
  __shared__ unsigned short S_lds[128 * 64];     // 16KB
  const unsigned short* QRb = QR + (long)bh * TSEQ * 256;
  const unsigned short* Vtb = Vt + (long)bh * 512 * TSEQ;
  float* yb = Y + (long)bh * TSEQ * 512;
  int lin_base = wave * 4096 + lane * 16;

#pragma unroll 1
  for (int half = 0; half < 2; ++half) {
    int bt = half ? bp : (15 - bp);
    int t0 = bt * 128;
    int nst = 2 * bt + 2;

    bf16x8 qa[8];
    {
      int trow = t0 + wave * 16 + l16;
      const unsigned short* qp = QRb + (long)trow * 256 + khi * 8;
#pragma unroll
      for (int ks = 0; ks < 8; ++ks) qa[ks] = *(const bf16x8*)(qp + ks * 32);
    }
    f32x4 acc[4][8] = {};

    // prologue: stage K tile st=0 into buffer 0
#pragma unroll
    for (int q = 0; q < 4; ++q) {
      int linear = lin_base + q * 1024;
      int row = linear >> 9;
      int nc2 = (linear & 511) ^ ((row & 7) << 4);
      __builtin_amdgcn_global_load_lds(
          (const g_uint*)((const char*)QRb + (long)row * 512 + nc2),
          (lds_uint*)((char*)K_lds[0] + (wave * 4 + q) * 1024), 16, 0, 0);
    }
    __syncthreads();

    for (int st = 0; st < nst; ++st) {
      int s0 = st * 64;
      const char* Kcur = (const char*)K_lds[st & 1];

      if (st + 1 < nst) {
        long srow_base = (long)(s0 + 64) * 512;
        char* Knext = (char*)K_lds[(st + 1) & 1];
#pragma unroll
        for (int q = 0; q < 4; ++q) {
          int linear = lin_base + q * 1024;
          int row = linear >> 9;
          int nc2 = (linear & 511) ^ ((row & 7) << 4);
          __builtin_amdgcn_global_load_lds(
              (const g_uint*)((const char*)QRb + srow_base + (long)row * 512 + nc2),
              (lds_uint*)(Knext + (wave * 4 + q) * 1024), 16, 0, 0);
        }
      }

      // phase 1: S = Q K^T
      f32x4 sacc[4] = {};
#pragma unroll
      for (int ks = 0; ks < 8; ++ks) {
#pragma unroll
        for (int fc = 0; fc < 4; ++fc) {
          int srow = fc * 16 + l16;
          bf16x8 kf = *(const bf16x8*)(
              Kcur + srow * 512 + ((ks * 64 + khi * 16) ^ ((srow & 7) << 4)));
          sacc[fc] = mfma16(qa[ks], kf, sacc[fc]);
        }
      }
#pragma unroll
      for (int fc = 0; fc < 4; ++fc)
#pragma unroll
        for (int r = 0; r < 4; ++r) {
          int srow = wave * 16 + khi * 4 + r;
          int scol = fc * 16 + l16;
          float v = ((s0 + scol) < (t0 + srow)) ? sacc[fc][r] : 0.f;
          *(unsigned short*)(
              (char*)S_lds + srow * 128 + ((scol * 2) ^ ((srow & 7) << 4))) = f2bf(v);
        }
      __syncthreads();   // S ready

      // phase 2: O += S @ V over full 512 d
#pragma unroll
      for (int k2 = 0; k2 < 2; ++k2) {
        bf16x8 af[4];
#pragma unroll
        for (int mi = 0; mi < 4; ++mi) {
          int row = wr * 64 + mi * 16 + l16;
          af[mi] = *(const bf16x8*)(
              (const char*)S_lds + row * 128 + ((k2 * 64 + khi * 16) ^ ((row & 7) << 4)));
        }
#pragma unroll
        for (int nh = 0; nh < 2; ++nh) {
          bf16x8 bfv[4];
#pragma unroll
          for (int nj = 0; nj < 4; ++nj) {
            int d = wc * 128 + (nh * 4 + nj) * 16 + l16;
            bfv[nj] = *(const bf16x8*)(Vtb + (long)d * TSEQ + s0 + k2 * 32 + khi * 8);
          }
#pragma unroll
          for (int mi = 0; mi < 4; ++mi)
#pragma unroll
            for (int nj = 0; nj < 4; ++nj)
              acc[mi][nh * 4 + nj] = mfma16(af[mi], bfv[nj], acc[mi][nh * 4 + nj]);
        }
      }
      __syncthreads();   // K_lds[st+1] landed (vmcnt drain), S_lds reads done
    }

#pragma unroll
    for (int mi = 0; mi < 4; ++mi)
#pragma unroll
      for (int ni = 0; ni < 8; ++ni)
#pragma unroll
        for (int r = 0; r < 4; ++r) {
          int trow = t0 + wr * 64 + mi * 16 + khi * 4 + r;
          int d = wc * 128 + ni * 16 + l16;
          yb[(long)trow * 512 + d] = acc[mi][ni][r];
        }
  }
}

// ---------------- Kernel 7: y_memory GEMM + LN + gated combine ----------
__global__ __launch_bounds__(512) void combine_kernel(
    const unsigned short* __restrict__ Qm,
    const unsigned short* __restrict__ M0t,
    const float* __restrict__ mg,
    float* __restrict__ Y) {
  int t0 = blockIdx.x * 64;
  int bh = blockIdx.y;
  int b = bh >> 3, h = bh & 7;
  int wv = threadIdx.x >> 6, lane = threadIdx.x & 63;
  int khi = lane >> 4, l16 = lane & 15;
  __shared__ unsigned short A_lds[64 * 256];
  __shared__ float red_s[8][64], red_q[8][64];
  __shared__ float mu_s[64], inv_s[64];
  {
    const unsigned short* src = Qm + ((long)b * TSEQ + t0) * 256;
#pragma unroll
    for (int p = 0; p < 4; ++p) {
      int row = (threadIdx.x >> 5) + p * 16;
      int nc = (threadIdx.x & 31) * 8;
      bf16x8 v = *reinterpret_cast<const bf16x8*>(src + (long)row * 256 + nc);
      *reinterpret_cast<bf16x8*>((char*)A_lds + row * 512 + ((nc * 2) ^ ((row & 7) << 4))) = v;
    }
  }
  __syncthreads();
  f32x4 acc[4][4] = {};
  const unsigned short* Bp = M0t + (long)bh * 512 * 256;
#pragma unroll
  for (int ks = 0; ks < 8; ++ks) {
    bf16x8 a[4], bfr[4];
#pragma unroll
    for (int mi = 0; mi < 4; ++mi) {
      int row = mi * 16 + l16;
      a[mi] = *reinterpret_cast<const bf16x8*>(
          (const char*)A_lds + row * 512 + ((ks * 64 + khi * 16) ^ ((row & 7) << 4)));
    }
#pragma unroll
    for (int ni = 0; ni < 4; ++ni) {
      int d = wv * 64 + ni * 16 + l16;
      bfr[ni] = *reinterpret_cast<const bf16x8*>(Bp + (long)d * 256 + ks * 32 + khi * 8);
    }
#pragma unroll
    for (int mi = 0; mi < 4; ++mi)
#pragma unroll
      for (int ni = 0; ni < 4; ++ni)
        acc[mi][ni] = mfma16(a[mi], bfr[ni], acc[mi][ni]);
  }
  float ps[4][4], pq[4][4];
#pragma unroll
  for (int mi = 0; mi < 4; ++mi)
#pragma unroll
    for (int r = 0; r < 4; ++r) {
      float s = 0.f, q = 0.f;
#pragma unroll
      for (int ni = 0; ni < 4; ++ni) {
        float v = acc[mi][ni][r];
        s += v; q += v * v;
      }
      ps[mi][r] = s; pq[mi][r] = q;
    }
#pragma unroll
  for (int off = 1; off < 16; off <<= 1)
#pragma unroll
    for (int mi = 0; mi < 4; ++mi)
#pragma unroll
      for (int r = 0; r < 4; ++r) {
        ps[mi][r] += __shfl_xor(ps[mi][r], off);
        pq[mi][r] += __shfl_xor(pq[mi][r], off);
      }
  if (l16 == 0) {
#pragma unroll
    for (int mi = 0; mi < 4; ++mi)
#pragma unroll
      for (int r = 0; r < 4; ++r) {
        int row = mi * 16 + khi * 4 + r;
        red_s[wv][row] = ps[mi][r];
        red_q[wv][row] = pq[mi][r];
      }
  }
  __syncthreads();
  if (threadIdx.x < 64) {
    float s = 0.f, q = 0.f;
#pragma unroll
    for (int w2 = 0; w2 < 8; ++w2) { s += red_s[w2][threadIdx.x]; q += red_q[w2][threadIdx.x]; }
    float mu = s / 512.f;
    float var = q / 512.f - mu * mu;
    mu_s[threadIdx.x] = mu;
    inv_s[threadIdx.x] = rsqrtf(var + 1e-5f);
  }
  __syncthreads();
  float gate = 1.f / (1.f + expf(-mg[h]));
  float omg = 1.f - gate;
  float* yb = Y + ((long)bh * TSEQ + t0) * 512;
#pragma unroll
  for (int mi = 0; mi < 4; ++mi)
#pragma unroll
    for (int r = 0; r < 4; ++r) {
      int row = mi * 16 + khi * 4 + r;
      float mu = mu_s[row], inv = inv_s[row];
#pragma unroll
      for (int ni = 0; ni < 4; ++ni) {
        int d = wv * 64 + ni * 16 + l16;
        long off = (long)row * 512 + d;
        float ymv = (acc[mi][ni][r] - mu) * inv;
        yb[off] = omg * yb[off] + gate * ymv;
      }
    }
}

// ---------------- host launcher -----------------------------------------
extern "C" void kernel_launch(void* const* d_in, const int* in_sizes, int n_in,
                              void* d_out, int out_size, void* d_ws, size_t ws_size,
                              hipStream_t stream) {
  const float* Q      = (const float*)d_in[0];
  const float* V      = (const float*)d_in[1];
  const float* x_raw  = (const float*)d_in[2];
  const float* x_next = (const float*)d_in[3];
  const float* wq     = (const float*)d_in[4];
  const float* wk     = (const float*)d_in[5];
  const float* bw     = (const float*)d_in[6];
  const float* mg     = (const float*)d_in[7];
  const float* M0     = (const float*)d_in[8];
  float* y = (float*)d_out;
  float* Mout = y + (long)32 * 2048 * 512;

  char* ws = (char*)d_ws;
  unsigned short* QR  = (unsigned short*)(ws);                 // 33,554,432 B
  unsigned short* Vt  = (unsigned short*)(ws + 33554432);      // 67,108,864 B
  unsigned short* M0t = (unsigned short*)(ws + 100663296);     //  8,388,608 B
  unsigned short* Qm  = (unsigned short*)(ws + 109051904);     //  4,194,304 B
  float*  Km          = (float*)(ws + 113246208);              //  8,388,608 B
  float*  beta        = (float*)(ws + 121634816);              //    262,144 B
  // Aliased inside the Vt region (all consumed before transposeV writes Vt):
  unsigned short* Whi = (unsigned short*)(ws + 33554432);      //  8,388,608 B
  unsigned short* Wlo = (unsigned short*)(ws + 41943040);      //  8,388,608 B
  unsigned short* Kmb = (unsigned short*)(ws + 50331648);      //  4,194,304 B
  unsigned short* KmT = (unsigned short*)(ws + 54525952);      //  4,194,304 B

  qkm_kernel<<<dim3(128, 2), dim3(512), 0, stream>>>(x_raw, wq, wk, Qm, Km, Kmb);
  transpose_cast_kernel<<<dim3(4, 32, 4), dim3(256), 0, stream>>>(Km, KmT, 2048, 256);
  beta_kernel<<<dim3(8192), dim3(64), 0, stream>>>(x_raw, bw, beta);
  wprep_kernel<<<dim3(1024), dim3(256), 0, stream>>>(Km, beta, Whi, Wlo);
  cscan_kernel<<<dim3(32, 8), dim3(512), 0, stream>>>(Kmb, KmT, x_next, M0, Whi, Wlo, Mout);
  rope_kernel<<<dim3(32768), dim3(256), 0, stream>>>(Q, QR);
  transpose_cast_kernel<<<dim3(8, 32, 32), dim3(256), 0, stream>>>(V, Vt, 2048, 512);
  transpose_cast_kernel<<<dim3(8, 4, 32), dim3(256), 0, stream>>>(M0, M0t, 256, 512);
  attn_kernel<<<dim3(32, 8), dim3(512), 0, stream>>>(QR, Vt, y);
  combine_kernel<<<dim3(32, 32), dim3(512), 0, stream>>>(Qm, M0t, mg, y);
}